// Round 12
// baseline (1798.147 us; speedup 1.0000x reference)
//
#include <hip/hip_runtime.h>
#include <hip/hip_bf16.h>
#include <math.h>

#define B_ 128
#define N_ 2048
#define D_ 512
#define H_ 512

#define NEG_BIG (-1.0e30f)

typedef unsigned int uint;
typedef unsigned short ushort;

// ws layout (float offsets)
#define WS_INP  0
#define WS_ATT  (WS_INP + B_*H_)          // 65536
#define WS_M    (WS_ATT + B_*N_)          // +262144
#define WS_FLAG (WS_M + B_*D_)            // +65536
#define WS_BP   393280                    // 16B aligned; Bpack = 524288 ushort = 1MB
#define WS_NEED_FLOATS (WS_BP + 262144)

typedef __attribute__((ext_vector_type(4))) float  f32x4;
typedef __attribute__((ext_vector_type(8))) short  bf16x8;

union BF8 { unsigned short u[8]; bf16x8 v; };

__device__ __forceinline__ ushort f2bf(float x) {
    uint u = __float_as_uint(x);
    u = (u + 0x7fffu + ((u >> 16) & 1u)) >> 16;   // RNE; inputs finite
    return (ushort)u;
}
__device__ __forceinline__ float bf2f(ushort h) {
    return __uint_as_float(((uint)h) << 16);
}
__device__ __forceinline__ float fast_tanh(float x) {
    return 1.0f - 2.0f / (1.0f + __expf(2.0f * x));
}

// ---------------------------------------------------------------------------
__global__ void detect_mask(const uint* __restrict__ mask_raw,
                            int* __restrict__ flag) {
    int lane = threadIdx.x;                 // 64 threads = 1 wave
    uint v = mask_raw[lane];
    unsigned long long m = __ballot(v <= 1u);
    if (lane == 0) *flag = (m == ~0ull) ? 1 : 0;
}

// ---------------------------------------------------------------------------
__global__ __launch_bounds__(256) void linear_kernel(
        const float* __restrict__ a, const float* __restrict__ W,
        const float* __restrict__ bias, float* __restrict__ out) {
    int idx = blockIdx.x * 256 + threadIdx.x;
    int b = idx >> 9;
    int h = idx & (H_ - 1);
    const float4* ar = (const float4*)(a + (size_t)b * D_);
    const float4* wr = (const float4*)(W + (size_t)h * D_);
    float acc = 0.f;
#pragma unroll 4
    for (int d = 0; d < D_ / 4; ++d) {
        float4 av = ar[d], wv = wr[d];
        acc = fmaf(av.x, wv.x, acc);
        acc = fmaf(av.y, wv.y, acc);
        acc = fmaf(av.z, wv.z, acc);
        acc = fmaf(av.w, wv.w, acc);
    }
    out[idx] = acc + bias[h];
}

// ---------------------------------------------------------------------------
// Pre-pack Wc into MFMA B-fragment-linear bf16 hi/lo (RNE).
__global__ __launch_bounds__(256) void pack_wc(const float* __restrict__ Wc,
                                               ushort* __restrict__ Bp) {
    int tid = blockIdx.x * 256 + threadIdx.x;       // 32768 threads
    int lane = tid & 63;
    int fs   = tid >> 6;
    int hf = fs >> 4, ks = fs & 15;
    int h  = hf * 16 + (lane & 15);
    int k0 = ks * 32 + (lane >> 4) * 8;
    const float* src = Wc + (size_t)h * D_ + k0;
    BF8 hi, lo;
#pragma unroll
    for (int j = 0; j < 8; ++j) {
        float x = src[j];
        hi.u[j] = f2bf(x);
        lo.u[j] = f2bf(x - bf2f(hi.u[j]));
    }
    *(bf16x8*)(Bp + (size_t)tid * 8)          = hi.v;
    *(bf16x8*)(Bp + 262144 + (size_t)tid * 8) = lo.v;
}

// ---------------------------------------------------------------------------
// Split-bf16 3-product MFMA. BM=256, full H=512, 512 thr / 8 waves (2r x 4c);
// wave tile 128x128 -> acc[8][8] = 256 AGPRs (+~120 VGPR of the unified 512
// file, still 2 waves/SIMD). Doubling BM doubles MFMA work per phase while
// B ds_reads / DMA / barrier cost stay constant -> MFMA:LDS ratio 2.7:1.
// A: reg->trunc-split->LDS, SINGLE buffer 32KB (mid-phase barrier protects).
// B: DMA from L2-hot Bpack, double-buffered 128KB. LDS = 160KB exactly.
// Race-free: end-of-phase __syncthreads (vmcnt0) covers cross-wave DMA.
#define KP  32
#define NPH 16

#define DMA_B(p, bi) do {                                                       \
    _Pragma("unroll")                                                           \
    for (int i_ = 0; i_ < 8; ++i_) {                                            \
        int c_  = w * 8 + i_;                                                   \
        int hf_ = c_ & 31;                                                      \
        const ushort* g_ = Bp + (c_ >= 32 ? 262144 : 0)                         \
                         + (size_t)((hf_ << 4) + (p)) * 512 + lane * 8;         \
        ushort* l_ = (c_ >= 32 ? sBl[bi] : sBh[bi]) + hf_ * 512;                \
        __builtin_amdgcn_global_load_lds(                                       \
            (const __attribute__((address_space(1))) unsigned int*)g_,          \
            (__attribute__((address_space(3))) unsigned int*)l_, 16, 0, 0);     \
    }                                                                           \
} while (0)

// 16 floats (4 uint4) -> hi/lo bf16, 2 groups of 8, into single-buffered A
#define PK_HI(a_, b_) ((b_ & 0xFFFF0000u) | (a_ >> 16))
#define LO_F(a_) (__uint_as_float(a_) - __uint_as_float(a_ & 0xFFFF0000u))
#define PK_LO(ra_, rb_) ((__float_as_uint(rb_) & 0xFFFF0000u) | (__float_as_uint(ra_) >> 16))
#define STAGE_A4(X0, X1, X2, X3) do {                                           \
    uint h0_ = PK_HI(X0.x, X0.y), h1_ = PK_HI(X0.z, X0.w);                      \
    uint h2_ = PK_HI(X1.x, X1.y), h3_ = PK_HI(X1.z, X1.w);                      \
    uint h4_ = PK_HI(X2.x, X2.y), h5_ = PK_HI(X2.z, X2.w);                      \
    uint h6_ = PK_HI(X3.x, X3.y), h7_ = PK_HI(X3.z, X3.w);                      \
    float r0_ = LO_F(X0.x), r1_ = LO_F(X0.y), r2_ = LO_F(X0.z), r3_ = LO_F(X0.w); \
    float r4_ = LO_F(X1.x), r5_ = LO_F(X1.y), r6_ = LO_F(X1.z), r7_ = LO_F(X1.w); \
    float r8_ = LO_F(X2.x), r9_ = LO_F(X2.y), rA_ = LO_F(X2.z), rB_ = LO_F(X2.w); \
    float rC_ = LO_F(X3.x), rD_ = LO_F(X3.y), rE_ = LO_F(X3.z), rF_ = LO_F(X3.w); \
    *(uint4*)((char*)sAh + awb0) = make_uint4(h0_, h1_, h2_, h3_);              \
    *(uint4*)((char*)sAh + awb1) = make_uint4(h4_, h5_, h6_, h7_);              \
    *(uint4*)((char*)sAl + awb0) = make_uint4(PK_LO(r0_, r1_), PK_LO(r2_, r3_), \
                                              PK_LO(r4_, r5_), PK_LO(r6_, r7_));\
    *(uint4*)((char*)sAl + awb1) = make_uint4(PK_LO(r8_, r9_), PK_LO(rA_, rB_), \
                                              PK_LO(rC_, rD_), PK_LO(rE_, rF_));\
} while (0)

#define MM(a_, b_, c_) __builtin_amdgcn_mfma_f32_16x16x32_bf16(a_, b_, c_, 0, 0, 0)

__global__ __launch_bounds__(512, 2) void att_mfma_kernel(
        const float* __restrict__ ctx, const ushort* __restrict__ Bp,
        const float* __restrict__ bc, const float* __restrict__ V,
        const float* __restrict__ inp, float* __restrict__ att) {
    __shared__ ushort sAh[8192];       // 16KB [rowfrag16][lane64][8], single buf
    __shared__ ushort sAl[8192];       // 16KB
    __shared__ ushort sBh[2][16384];   // 64KB [buf][hf32][lane64][8]
    __shared__ ushort sBl[2][16384];   // 64KB

    const int t    = threadIdx.x;
    const int lane = t & 63;
    const int w    = t >> 6;
    const int wr   = w >> 2;               // row half (128 rows)
    const int wc   = w & 3;                // col group (128 cols)
    const int g0   = blockIdx.x * 256;
    const int b    = g0 >> 11;             // uniform per block (256 | 2048)

    // A staging: thread -> row t>>1, K-half (t&1)*16 of the 32-wide phase
    const int srow = t >> 1;
    const int skh  = t & 1;
    const float* gAs = ctx + (size_t)(g0 + srow) * D_ + skh * 16;
    const int rfb  = (srow >> 4) * 1024;   // byte base of row-frag
    const int awb0 = rfb + (((srow & 15) + (skh * 2 + 0) * 16) << 4);
    const int awb1 = rfb + (((srow & 15) + (skh * 2 + 1) * 16) << 4);

    f32x4 acc[8][8] = {};

    // prologue: A(0) + B(0)
    {
        uint4 X0 = *(const uint4*)(gAs + 0);
        uint4 X1 = *(const uint4*)(gAs + 4);
        uint4 X2 = *(const uint4*)(gAs + 8);
        uint4 X3 = *(const uint4*)(gAs + 12);
        DMA_B(0, 0);
        STAGE_A4(X0, X1, X2, X3);
        __syncthreads();                   // full drain: B(0)+A(0) visible
    }

    for (int p = 0; p < NPH; ++p) {
        const int buf = p & 1;
        const int pn  = (p + 1) & 15;      // uniform; last prefetch dead
        const ushort* pBh = sBh[buf];
        const ushort* pBl = sBl[buf];

        // A fragments for this phase (conflict-free lane-linear b128)
        bf16x8 ah[8], al[8];
#pragma unroll
        for (int rf = 0; rf < 8; ++rf) {
            const int o = (wr * 8 + rf) * 1024 + lane * 16;
            ah[rf] = *(const bf16x8*)((const char*)sAh + o);
            al[rf] = *(const bf16x8*)((const char*)sAl + o);
        }

        // prefetch next A (regs) + DMA next B (other buffer)
        uint4 X0 = *(const uint4*)(gAs + pn * KP);
        uint4 X1 = *(const uint4*)(gAs + pn * KP + 4);
        uint4 X2 = *(const uint4*)(gAs + pn * KP + 8);
        uint4 X3 = *(const uint4*)(gAs + pn * KP + 12);
        DMA_B(pn, buf ^ 1);

        __builtin_amdgcn_s_setprio(1);
#pragma unroll
        for (int cf = 0; cf < 8; ++cf) {
            const int bo = (wc * 8 + cf) * 512 + lane * 8;
            bf16x8 bh = *(const bf16x8*)(pBh + bo);
            bf16x8 bl = *(const bf16x8*)(pBl + bo);
#pragma unroll
            for (int rf = 0; rf < 8; ++rf) {
                acc[rf][cf] = MM(ah[rf], bh, acc[rf][cf]);
                acc[rf][cf] = MM(ah[rf], bl, acc[rf][cf]);
                acc[rf][cf] = MM(al[rf], bh, acc[rf][cf]);
            }
        }
        __builtin_amdgcn_s_setprio(0);

        __builtin_amdgcn_sched_barrier(0);
        __builtin_amdgcn_s_barrier();      // #1: all waves' A reads retired
        __builtin_amdgcn_sched_barrier(0);
        STAGE_A4(X0, X1, X2, X3);          // overwrite single A buffer
        __syncthreads();                   // #2: drains own DMA (landed) + lgkm
    }

    // epilogue: tanh + V-weight + reduce.  C/D: col=lane&15, row=(lane>>4)*4+j
    float P[8][4] = {};
#pragma unroll
    for (int cf = 0; cf < 8; ++cf) {
        const int h = wc * 128 + cf * 16 + (lane & 15);
        const float sh = inp[b * H_ + h] + bc[h];
        const float vh = V[h];
#pragma unroll
        for (int rf = 0; rf < 8; ++rf)
#pragma unroll
            for (int j = 0; j < 4; ++j)
                P[rf][j] += vh * fast_tanh(acc[rf][cf][j] + sh);
    }
#pragma unroll
    for (int rf = 0; rf < 8; ++rf)
#pragma unroll
        for (int j = 0; j < 4; ++j) {
            float x = P[rf][j];
            x += __shfl_xor(x, 1); x += __shfl_xor(x, 2);
            x += __shfl_xor(x, 4); x += __shfl_xor(x, 8);
            P[rf][j] = x;
        }

    float (*red)[128] = (float(*)[128])sAh;   // 4KB overlay (A dead)
    if ((lane & 15) == 0) {
        const int kc = lane >> 4;
#pragma unroll
        for (int rf = 0; rf < 8; ++rf)
#pragma unroll
            for (int j = 0; j < 4; ++j)
                red[w][rf * 16 + kc * 4 + j] = P[rf][j];
    }
    __syncthreads();
    if (t < 256) {
        const int wrr = (t >> 7) * 4, r = t & 127;
        att[g0 + t] = red[wrr + 0][r] + red[wrr + 1][r] + red[wrr + 2][r] + red[wrr + 3][r];
    }
}

// ---------------------------------------------------------------------------
__global__ __launch_bounds__(256) void softmax_kernel(
        const float* __restrict__ att, const void* __restrict__ mask,
        const int* __restrict__ flag, float* __restrict__ alpha,
        float* __restrict__ logp) {
    __shared__ float row[N_];
    __shared__ float red[4];
    const int b = blockIdx.x, t = threadIdx.x;
    const int is_int = *flag;
    const int* mi = (const int*)mask;
    const unsigned char* mb = (const unsigned char*)mask;

    float lmax = -INFINITY;
    for (int n = t; n < N_; n += 256) {
        bool m = is_int ? (mi[b * N_ + n] != 0) : (mb[b * N_ + n] != 0);
        float a = m ? NEG_BIG : att[b * N_ + n];
        row[n] = a;
        lmax = fmaxf(lmax, a);
    }
#pragma unroll
    for (int off = 32; off; off >>= 1) lmax = fmaxf(lmax, __shfl_down(lmax, off));
    if ((t & 63) == 0) red[t >> 6] = lmax;
    __syncthreads();
    const float rmax = fmaxf(fmaxf(red[0], red[1]), fmaxf(red[2], red[3]));
    __syncthreads();

    float lsum = 0.f;
    for (int n = t; n < N_; n += 256) lsum += __expf(row[n] - rmax);
#pragma unroll
    for (int off = 32; off; off >>= 1) lsum += __shfl_down(lsum, off);
    if ((t & 63) == 0) red[t >> 6] = lsum;
    __syncthreads();
    const float s = red[0] + red[1] + red[2] + red[3];
    const float inv = 1.0f / s;
    const float lse = logf(s);

    for (int n = t; n < N_; n += 256) {
        float a = row[n];
        alpha[b * N_ + n] = __expf(a - rmax) * inv;
        logp[b * N_ + n]  = a - rmax - lse;
    }
}

// ---------------------------------------------------------------------------
// m[b][d] = sum_n alpha[b][n]*ctx[b][n][d]; 512 thr: 4-way n-split per col.
__global__ __launch_bounds__(512) void wsum_kernel(
        const float* __restrict__ context, const float* __restrict__ alpha,
        float* __restrict__ m) {
    __shared__ float al[N_];
    __shared__ float part[3][128];
    const int c = blockIdx.x;          // d chunk (128 cols)
    const int b = blockIdx.y;
    const int t = threadIdx.x;
    for (int n = t; n < N_; n += 512) al[n] = alpha[(size_t)b * N_ + n];
    __syncthreads();
    const int d = c * 128 + (t & 127);
    const int q = t >> 7;              // n quarter
    const float* cp = context + (size_t)b * N_ * D_ + (size_t)q * 512 * D_ + d;
    const float* ap = al + q * 512;
    float acc = 0.f;
#pragma unroll 8
    for (int n = 0; n < 512; ++n) acc = fmaf(ap[n], cp[(size_t)n * D_], acc);
    if (q) part[q - 1][t & 127] = acc;
    __syncthreads();
    if (q == 0)
        m[b * D_ + d] = acc + part[0][t & 127] + part[1][t & 127] + part[2][t & 127];
}

// ---------------------------------------------------------------------------
extern "C" void kernel_launch(void* const* d_in, const int* in_sizes, int n_in,
                              void* d_out, int out_size, void* d_ws, size_t ws_size,
                              hipStream_t stream) {
    const float* x       = (const float*)d_in[0];
    const float* context = (const float*)d_in[1];
    const void*  mask    = d_in[2];
    const float* Wi      = (const float*)d_in[3];
    const float* bi      = (const float*)d_in[4];
    const float* Wc      = (const float*)d_in[5];
    const float* bc      = (const float*)d_in[6];
    const float* V       = (const float*)d_in[7];

    float* out  = (float*)d_out;
    float* ws   = (float*)d_ws;
    float* inp  = ws + WS_INP;
    float* att  = ws + WS_ATT;
    float* m    = ws + WS_M;
    int*   flag = (int*)(ws + WS_FLAG);

    float* hidden = out;
    float* alpha  = out + B_ * H_;
    float* logp   = alpha + B_ * N_;

    ushort* Bp =
        (ws_size >= (size_t)WS_NEED_FLOATS * 4) ? (ushort*)(ws + WS_BP)
                                                : (ushort*)logp;

    detect_mask<<<1, 64, 0, stream>>>((const uint*)mask, flag);
    linear_kernel<<<256, 256, 0, stream>>>(x, Wi, bi, inp);
    pack_wc<<<128, 256, 0, stream>>>(Wc, Bp);
    att_mfma_kernel<<<(B_ * N_) / 256, 512, 0, stream>>>(context, Bp, bc, V, inp, att);
    softmax_kernel<<<B_, 256, 0, stream>>>(att, mask, flag, alpha, logp);
    wsum_kernel<<<dim3(4, B_), 512, 0, stream>>>(context, alpha, m);
    linear_kernel<<<256, 256, 0, stream>>>(m, Wc, bc, hidden);
}

// Round 13
// 552.544 us; speedup vs baseline: 3.2543x; 3.2543x over previous
//
#include <hip/hip_runtime.h>
#include <hip/hip_bf16.h>
#include <math.h>

#define B_ 128
#define N_ 2048
#define D_ 512
#define H_ 512

#define NEG_BIG (-1.0e30f)

typedef unsigned int uint;
typedef unsigned short ushort;

// ws layout (float offsets)
#define WS_INP  0
#define WS_ATT  (WS_INP + B_*H_)          // 65536
#define WS_M    (WS_ATT + B_*N_)          // +262144
#define WS_FLAG (WS_M + B_*D_)            // +65536
#define WS_BP   393280                    // 16B aligned; Bpack = 524288 ushort = 1MB
#define WS_NEED_FLOATS (WS_BP + 262144)

typedef __attribute__((ext_vector_type(4))) float  f32x4;
typedef __attribute__((ext_vector_type(8))) short  bf16x8;

union BF8 { unsigned short u[8]; bf16x8 v; };

__device__ __forceinline__ ushort f2bf(float x) {
    uint u = __float_as_uint(x);
    u = (u + 0x7fffu + ((u >> 16) & 1u)) >> 16;   // RNE; inputs finite
    return (ushort)u;
}
__device__ __forceinline__ float bf2f(ushort h) {
    return __uint_as_float(((uint)h) << 16);
}
__device__ __forceinline__ float fast_tanh(float x) {
    return 1.0f - 2.0f / (1.0f + __expf(2.0f * x));
}

// ---------------------------------------------------------------------------
__global__ void detect_mask(const uint* __restrict__ mask_raw,
                            int* __restrict__ flag) {
    int lane = threadIdx.x;                 // 64 threads = 1 wave
    uint v = mask_raw[lane];
    unsigned long long m = __ballot(v <= 1u);
    if (lane == 0) *flag = (m == ~0ull) ? 1 : 0;
}

// ---------------------------------------------------------------------------
__global__ __launch_bounds__(256) void linear_kernel(
        const float* __restrict__ a, const float* __restrict__ W,
        const float* __restrict__ bias, float* __restrict__ out) {
    int idx = blockIdx.x * 256 + threadIdx.x;
    int b = idx >> 9;
    int h = idx & (H_ - 1);
    const float4* ar = (const float4*)(a + (size_t)b * D_);
    const float4* wr = (const float4*)(W + (size_t)h * D_);
    float acc = 0.f;
#pragma unroll 4
    for (int d = 0; d < D_ / 4; ++d) {
        float4 av = ar[d], wv = wr[d];
        acc = fmaf(av.x, wv.x, acc);
        acc = fmaf(av.y, wv.y, acc);
        acc = fmaf(av.z, wv.z, acc);
        acc = fmaf(av.w, wv.w, acc);
    }
    out[idx] = acc + bias[h];
}

// ---------------------------------------------------------------------------
// Pre-pack Wc into MFMA B-fragment-linear bf16 hi/lo (RNE).
__global__ __launch_bounds__(256) void pack_wc(const float* __restrict__ Wc,
                                               ushort* __restrict__ Bp) {
    int tid = blockIdx.x * 256 + threadIdx.x;       // 32768 threads
    int lane = tid & 63;
    int fs   = tid >> 6;
    int hf = fs >> 4, ks = fs & 15;
    int h  = hf * 16 + (lane & 15);
    int k0 = ks * 32 + (lane >> 4) * 8;
    const float* src = Wc + (size_t)h * D_ + k0;
    BF8 hi, lo;
#pragma unroll
    for (int j = 0; j < 8; ++j) {
        float x = src[j];
        hi.u[j] = f2bf(x);
        lo.u[j] = f2bf(x - bf2f(hi.u[j]));
    }
    *(bf16x8*)(Bp + (size_t)tid * 8)          = hi.v;
    *(bf16x8*)(Bp + 262144 + (size_t)tid * 8) = lo.v;
}

// ---------------------------------------------------------------------------
// Split-bf16 3-product MFMA. BM=128, full H=512, 1024 thr / 16 waves (4r x 4c)
// wave tile 32x128 -> acc[2][8] = 64 VGPR -> launch_bounds(1024,4): 4 waves
// per SIMD. Same per-SIMD MFMA work as the 8-wave version, but 4 staggered
// waves hide each other's frag-read heads (2 lockstep waves could not).
// A: reg->trunc-split->LDS double-buffered (32KB). B: DMA from L2-hot Bpack,
// double-buffered (128KB). LDS = 160KB exactly, 1 block/CU.
#define KP  32
#define NPH 16

#define DMA_B(p, bi) do {                                                       \
    _Pragma("unroll")                                                           \
    for (int i_ = 0; i_ < 4; ++i_) {                                            \
        int c_  = w * 4 + i_;                                                   \
        int hf_ = c_ & 31;                                                      \
        const ushort* g_ = Bp + (c_ >= 32 ? 262144 : 0)                         \
                         + (size_t)((hf_ << 4) + (p)) * 512 + lane * 8;         \
        ushort* l_ = (c_ >= 32 ? sBl[bi] : sBh[bi]) + hf_ * 512;                \
        __builtin_amdgcn_global_load_lds(                                       \
            (const __attribute__((address_space(1))) unsigned int*)g_,          \
            (__attribute__((address_space(3))) unsigned int*)l_, 16, 0, 0);     \
    }                                                                           \
} while (0)

// 4 floats -> hi/lo bf16 (truncation split), 8B each, to A buffer bi
#define STAGE_A1(Ux, bi) do {                                                   \
    uint h0_ = (Ux.y & 0xFFFF0000u) | (Ux.x >> 16);                             \
    uint h1_ = (Ux.w & 0xFFFF0000u) | (Ux.z >> 16);                             \
    float r0_ = __uint_as_float(Ux.x) - __uint_as_float(Ux.x & 0xFFFF0000u);    \
    float r1_ = __uint_as_float(Ux.y) - __uint_as_float(Ux.y & 0xFFFF0000u);    \
    float r2_ = __uint_as_float(Ux.z) - __uint_as_float(Ux.z & 0xFFFF0000u);    \
    float r3_ = __uint_as_float(Ux.w) - __uint_as_float(Ux.w & 0xFFFF0000u);    \
    uint l0_ = (__float_as_uint(r1_) & 0xFFFF0000u) | (__float_as_uint(r0_) >> 16); \
    uint l1_ = (__float_as_uint(r3_) & 0xFFFF0000u) | (__float_as_uint(r2_) >> 16); \
    *(uint2*)((char*)sAh[bi] + awb) = make_uint2(h0_, h1_);                     \
    *(uint2*)((char*)sAl[bi] + awb) = make_uint2(l0_, l1_);                     \
} while (0)

#define MM(a_, b_, c_) __builtin_amdgcn_mfma_f32_16x16x32_bf16(a_, b_, c_, 0, 0, 0)

__global__ __launch_bounds__(1024, 4) void att_mfma_kernel(
        const float* __restrict__ ctx, const ushort* __restrict__ Bp,
        const float* __restrict__ bc, const float* __restrict__ V,
        const float* __restrict__ inp, float* __restrict__ att) {
    __shared__ ushort sAh[2][4096];    // 16KB  [buf][rowfrag8][lane64][8]
    __shared__ ushort sAl[2][4096];    // 16KB
    __shared__ ushort sBh[2][16384];   // 64KB  [buf][hf32][lane64][8]
    __shared__ ushort sBl[2][16384];   // 64KB

    const int t    = threadIdx.x;
    const int lane = t & 63;
    const int w    = t >> 6;               // 0..15
    const int wr   = w >> 2;               // 32-row group
    const int wc   = w & 3;                // 128-col group
    const int g0   = blockIdx.x * 128;
    const int b    = g0 >> 11;             // uniform per block

    // A staging: thread -> row t>>3 (0..127), 4-float chunk kq = t&7
    const int srow = t >> 3;
    const int skq  = t & 7;
    const float* gAs = ctx + (size_t)(g0 + srow) * D_ + skq * 4;
    const int awb = ((((srow >> 4) * 64 + (srow & 15) + (skq >> 1) * 16) * 8
                      + (skq & 1) * 4)) * 2;   // byte offset in A buffer

    // A fragment read offsets (bytes): rowfrag = wr*2+rf, lane-linear b128
    const int ar0 = (wr * 2 + 0) * 1024 + lane * 16;
    const int ar1 = (wr * 2 + 1) * 1024 + lane * 16;

    f32x4 acc[2][8] = {};

    // prologue: A(0) + B(0)
    {
        uint4 X = *(const uint4*)(gAs);
        DMA_B(0, 0);
        STAGE_A1(X, 0);
        __syncthreads();
    }

    for (int p = 0; p < NPH; ++p) {
        const int buf = p & 1;
        const int pn  = (p + 1) & 15;      // uniform; last prefetch dead

        bf16x8 ah0 = *(const bf16x8*)((const char*)sAh[buf] + ar0);
        bf16x8 al0 = *(const bf16x8*)((const char*)sAl[buf] + ar0);
        bf16x8 ah1 = *(const bf16x8*)((const char*)sAh[buf] + ar1);
        bf16x8 al1 = *(const bf16x8*)((const char*)sAl[buf] + ar1);

        uint4 X = *(const uint4*)(gAs + pn * KP);  // next A chunk
        DMA_B(pn, buf ^ 1);                        // next B tile

        __builtin_amdgcn_s_setprio(1);
#pragma unroll
        for (int cf = 0; cf < 8; ++cf) {
            const int bo = (wc * 8 + cf) * 512 + lane * 8;
            bf16x8 bh = *(const bf16x8*)&sBh[buf][bo];
            bf16x8 bl = *(const bf16x8*)&sBl[buf][bo];
            acc[0][cf] = MM(ah0, bh, acc[0][cf]);
            acc[1][cf] = MM(ah1, bh, acc[1][cf]);
            acc[0][cf] = MM(ah0, bl, acc[0][cf]);
            acc[1][cf] = MM(ah1, bl, acc[1][cf]);
            acc[0][cf] = MM(al0, bh, acc[0][cf]);
            acc[1][cf] = MM(al1, bh, acc[1][cf]);
        }
        __builtin_amdgcn_s_setprio(0);

        STAGE_A1(X, buf ^ 1);               // stage next A (dbuf)
        __syncthreads();                    // drains DMA + lgkm (race-free)
    }

    // epilogue: tanh + V-weight + reduce.  C/D: col=lane&15, row=(lane>>4)*4+j
    float P[2][4] = {};
#pragma unroll
    for (int cf = 0; cf < 8; ++cf) {
        const int h = wc * 128 + cf * 16 + (lane & 15);
        const float sh = inp[b * H_ + h] + bc[h];
        const float vh = V[h];
#pragma unroll
        for (int rf = 0; rf < 2; ++rf)
#pragma unroll
            for (int j = 0; j < 4; ++j)
                P[rf][j] += vh * fast_tanh(acc[rf][cf][j] + sh);
    }
#pragma unroll
    for (int rf = 0; rf < 2; ++rf)
#pragma unroll
        for (int j = 0; j < 4; ++j) {
            float x = P[rf][j];
            x += __shfl_xor(x, 1); x += __shfl_xor(x, 2);
            x += __shfl_xor(x, 4); x += __shfl_xor(x, 8);
            P[rf][j] = x;
        }

    float (*red)[32] = (float(*)[32])sAh;   // 2KB overlay (A dead)
    if ((lane & 15) == 0) {
        const int kc = lane >> 4;
#pragma unroll
        for (int rf = 0; rf < 2; ++rf)
#pragma unroll
            for (int j = 0; j < 4; ++j)
                red[w][rf * 16 + kc * 4 + j] = P[rf][j];
    }
    __syncthreads();
    if (t < 128) {
        const int wr2 = t >> 5, r = t & 31;
        att[g0 + wr2 * 32 + r] = red[wr2 * 4 + 0][r] + red[wr2 * 4 + 1][r]
                               + red[wr2 * 4 + 2][r] + red[wr2 * 4 + 3][r];
    }
}

// ---------------------------------------------------------------------------
__global__ __launch_bounds__(256) void softmax_kernel(
        const float* __restrict__ att, const void* __restrict__ mask,
        const int* __restrict__ flag, float* __restrict__ alpha,
        float* __restrict__ logp) {
    __shared__ float row[N_];
    __shared__ float red[4];
    const int b = blockIdx.x, t = threadIdx.x;
    const int is_int = *flag;
    const int* mi = (const int*)mask;
    const unsigned char* mb = (const unsigned char*)mask;

    float lmax = -INFINITY;
    for (int n = t; n < N_; n += 256) {
        bool m = is_int ? (mi[b * N_ + n] != 0) : (mb[b * N_ + n] != 0);
        float a = m ? NEG_BIG : att[b * N_ + n];
        row[n] = a;
        lmax = fmaxf(lmax, a);
    }
#pragma unroll
    for (int off = 32; off; off >>= 1) lmax = fmaxf(lmax, __shfl_down(lmax, off));
    if ((t & 63) == 0) red[t >> 6] = lmax;
    __syncthreads();
    const float rmax = fmaxf(fmaxf(red[0], red[1]), fmaxf(red[2], red[3]));
    __syncthreads();

    float lsum = 0.f;
    for (int n = t; n < N_; n += 256) lsum += __expf(row[n] - rmax);
#pragma unroll
    for (int off = 32; off; off >>= 1) lsum += __shfl_down(lsum, off);
    if ((t & 63) == 0) red[t >> 6] = lsum;
    __syncthreads();
    const float s = red[0] + red[1] + red[2] + red[3];
    const float inv = 1.0f / s;
    const float lse = logf(s);

    for (int n = t; n < N_; n += 256) {
        float a = row[n];
        alpha[b * N_ + n] = __expf(a - rmax) * inv;
        logp[b * N_ + n]  = a - rmax - lse;
    }
}

// ---------------------------------------------------------------------------
// m[b][d] = sum_n alpha[b][n]*ctx[b][n][d]; 512 thr: 4-way n-split per col.
__global__ __launch_bounds__(512) void wsum_kernel(
        const float* __restrict__ context, const float* __restrict__ alpha,
        float* __restrict__ m) {
    __shared__ float al[N_];
    __shared__ float part[3][128];
    const int c = blockIdx.x;          // d chunk (128 cols)
    const int b = blockIdx.y;
    const int t = threadIdx.x;
    for (int n = t; n < N_; n += 512) al[n] = alpha[(size_t)b * N_ + n];
    __syncthreads();
    const int d = c * 128 + (t & 127);
    const int q = t >> 7;              // n quarter
    const float* cp = context + (size_t)b * N_ * D_ + (size_t)q * 512 * D_ + d;
    const float* ap = al + q * 512;
    float acc = 0.f;
#pragma unroll 8
    for (int n = 0; n < 512; ++n) acc = fmaf(ap[n], cp[(size_t)n * D_], acc);
    if (q) part[q - 1][t & 127] = acc;
    __syncthreads();
    if (q == 0)
        m[b * D_ + d] = acc + part[0][t & 127] + part[1][t & 127] + part[2][t & 127];
}

// ---------------------------------------------------------------------------
extern "C" void kernel_launch(void* const* d_in, const int* in_sizes, int n_in,
                              void* d_out, int out_size, void* d_ws, size_t ws_size,
                              hipStream_t stream) {
    const float* x       = (const float*)d_in[0];
    const float* context = (const float*)d_in[1];
    const void*  mask    = d_in[2];
    const float* Wi      = (const float*)d_in[3];
    const float* bi      = (const float*)d_in[4];
    const float* Wc      = (const float*)d_in[5];
    const float* bc      = (const float*)d_in[6];
    const float* V       = (const float*)d_in[7];

    float* out  = (float*)d_out;
    float* ws   = (float*)d_ws;
    float* inp  = ws + WS_INP;
    float* att  = ws + WS_ATT;
    float* m    = ws + WS_M;
    int*   flag = (int*)(ws + WS_FLAG);

    float* hidden = out;
    float* alpha  = out + B_ * H_;
    float* logp   = alpha + B_ * N_;

    ushort* Bp =
        (ws_size >= (size_t)WS_NEED_FLOATS * 4) ? (ushort*)(ws + WS_BP)
                                                : (ushort*)logp;

    detect_mask<<<1, 64, 0, stream>>>((const uint*)mask, flag);
    linear_kernel<<<256, 256, 0, stream>>>(x, Wi, bi, inp);
    pack_wc<<<128, 256, 0, stream>>>(Wc, Bp);
    att_mfma_kernel<<<(B_ * N_) / 128, 1024, 0, stream>>>(context, Bp, bc, V, inp, att);
    softmax_kernel<<<B_, 256, 0, stream>>>(att, mask, flag, alpha, logp);
    wsum_kernel<<<dim3(4, B_), 512, 0, stream>>>(context, alpha, m);
    linear_kernel<<<256, 256, 0, stream>>>(m, Wc, bc, hidden);
}